// Round 2
// baseline (3835.527 us; speedup 1.0000x reference)
//
#include <hip/hip_runtime.h>

#define NPTS 256
#define NBATCH 64
#define BIGF 1e30f
#define KBIG 0x7149F200u   // __float_as_uint(1e30f) & 0xFFFFFF00

__device__ __forceinline__ float rlane(float v, int l) {
    return __uint_as_float((unsigned int)__builtin_amdgcn_readlane((int)__float_as_uint(v), l));
}
__device__ __forceinline__ int rlanei(int v, int l) {
    return __builtin_amdgcn_readlane(v, l);
}
__device__ __forceinline__ float rawsqrt(float x) {
    return __builtin_amdgcn_sqrtf(x);
}

// Uniform-slot select (slot wave-uniform); cold paths only.
#define SEL4(a, s) ((s) == 0 ? a[0] : (s) == 1 ? a[1] : (s) == 2 ? a[2] : a[3])

#define DPP_UMIN(v, ctrl) \
    (min)((v), (unsigned int)__builtin_amdgcn_update_dpp( \
        (int)(v), (int)(v), (ctrl), 0xf, 0xf, false))

__global__ void zero_out_kernel(float* out, int n) {
    int i = blockIdx.x * blockDim.x + threadIdx.x;
    if (i < n) out[i] = 0.0f;
}

// ---- R15 hot loop, rotated into EXTRACT / RELAX halves (same dataflow as R13's
// EXPAND_ONCE, which was extract-after-relax; multi-source needs extract-first
// since keys are pre-seeded by the source sweep). Reduce = 3 DPP row_shr
// (8-block minima in lanes 7,15,..,63) + 8 parallel readlanes + SALU min tree.
// `break` exits the enclosing while on augment.

#define EXTRACT_ONCE                                                             \
    {                                                                            \
        unsigned int vr = (min)((min)(kMv[0], kMv[1]), (min)(kMv[2], kMv[3]));   \
        vr = DPP_UMIN(vr, 0x111);   /* row_shr:1 */                              \
        vr = DPP_UMIN(vr, 0x112);   /* row_shr:2 */                              \
        vr = DPP_UMIN(vr, 0x114);   /* row_shr:4 */                              \
        const unsigned int q0 = (unsigned int)rlanei((int)vr, 7);                \
        const unsigned int q1 = (unsigned int)rlanei((int)vr, 15);               \
        const unsigned int q2 = (unsigned int)rlanei((int)vr, 23);               \
        const unsigned int q3 = (unsigned int)rlanei((int)vr, 31);               \
        const unsigned int q4 = (unsigned int)rlanei((int)vr, 39);               \
        const unsigned int q5 = (unsigned int)rlanei((int)vr, 47);               \
        const unsigned int q6 = (unsigned int)rlanei((int)vr, 55);               \
        const unsigned int q7 = (unsigned int)rlanei((int)vr, 63);               \
        const unsigned int kk = (min)((min)((min)(q0, q1), (min)(q2, q3)),       \
                                      (min)((min)(q4, q5), (min)(q6, q7)));      \
        const int   j1   = (int)(kk & 0xFFu);                                    \
        const float gmin = __uint_as_float(kk & 0xFFFFFF00u);                    \
        const int osl = j1 >> 6, oln = j1 & 63;                                  \
        float uj, nbx, nby, nbz;                                                 \
        switch (osl) {                                                           \
            case 0:  uj = rlane(upc[0], oln); nbx = rlane(rxc[0], oln); nby = rlane(ryc[0], oln); nbz = rlane(rzc[0], oln); break; \
            case 1:  uj = rlane(upc[1], oln); nbx = rlane(rxc[1], oln); nby = rlane(ryc[1], oln); nbz = rlane(rzc[1], oln); break; \
            case 2:  uj = rlane(upc[2], oln); nbx = rlane(rxc[2], oln); nby = rlane(ryc[2], oln); nbz = rlane(rzc[2], oln); break; \
            default: uj = rlane(upc[3], oln); nbx = rlane(rxc[3], oln); nby = rlane(ryc[3], oln); nbz = rlane(rzc[3], oln); break; \
        }                                                                        \
        const unsigned long long fm =                                            \
            (osl == 0 ? freem[0] : osl == 1 ? freem[1] : osl == 2 ? freem[2] : freem[3]); \
        if ((fm >> oln) & 1ull) { jfin = j1; D = gmin; break; }                  \
        _Pragma("unroll")                                                        \
        for (int c = 0; c < 4; ++c)                                              \
            if (c == osl && lane == oln) {                                       \
                usedm |= (1 << c);                                               \
                Tv[c] = gmin;                                                    \
                vsave[c] = vv[c];                                                \
                vv[c] = -BIGF;                 /* -> w = +BIGF -> excluded */    \
                kMv[c] = KBIG | colu[c];       /* frozen */                      \
            }                                                                    \
        const float gu = gmin - uj;                                              \
        _Pragma("unroll")                                                        \
        for (int c = 0; c < 4; ++c) w[c] = gu - vv[c];                           \
        bx = nbx; by = nby; bz = nbz;                                            \
        j0 = j1;                                                                 \
    }

#define RELAX_ONCE                                                               \
    {                                                                            \
        _Pragma("unroll")                                                        \
        for (int c = 0; c < 4; ++c) {                                            \
            float dx = bx - tx[c], dy = by - ty[c], dz = bz - tz[c];             \
            float d = rawsqrt(dx * dx + dy * dy + dz * dz);                      \
            float cand = d + w[c];              /* cumulative dist via delta */  \
            unsigned int kc = (__float_as_uint(cand) & 0xFFFFFF00u) | colu[c];   \
            if (kc < kMv[c]) { kMv[c] = kc; way[c] = j0; }                       \
        }                                                                        \
    }

// One wave per batch; lane owns columns/rows {lane, 64+lane, 128+lane, 192+lane}.
// R15 = R13 base (R14's transfer/ARR REMOVED: dual strengthening falsified —
// +406us, zero tree shrink) with Phase 2 switched from one-Dijkstra-per-free-row
// to MULTI-SOURCE successive shortest paths: each search starts from the virtual
// super-source over ALL free rows (keys = min_i free (d(i,j) - v_j), u_free=0,
// srcrow[j] = argmin source), stops at the first free column, augments. Exact
// (standard SSP for min-cost flow); dual-commit formula verified unchanged for
// the multi-source case (source row gets u = D; way==-1 columns backtrace to
// srcrow). Early searches terminate in ~1 step; total extractions drop ~an
// order of magnitude vs single-source near-full trees.
__launch_bounds__(64, 1)
__global__ void hungarian_wave(const float* __restrict__ pred,
                               const float* __restrict__ target,
                               float* __restrict__ out) {
    const int b    = blockIdx.x;
    const int lane = threadIdx.x;

    const float* pb = pred   + (size_t)b * NPTS * 3;
    const float* tb = target + (size_t)b * NPTS * 3;

    float prx[4], pry[4], prz[4];      // pred (row) points, row = c*64+lane
    float tx[4], ty[4], tz[4];         // target (col) points, col = c*64+lane
    float vv[4], upc[4], Tv[4], w[4], vsave[4];
    float rxc[4], ryc[4], rzc[4];      // matched-row coords, column-attached
    unsigned int kMv[4];               // packed slack keys: (bits(M)&~0xFF)|col
    int   pc[4]  = {-1, -1, -1, -1};   // matched row per column (-1 = free)
    int   way[4];
    int   srcrow[4];                   // multi-source: seeding free row per column
    unsigned int colu[4];              // this lane's column ids
    unsigned long long freem[4];       // free-COLUMN masks (wave-uniform)

#pragma unroll
    for (int c = 0; c < 4; ++c) {
        int idx = c * 64 + lane;
        prx[c] = pb[idx * 3 + 0]; pry[c] = pb[idx * 3 + 1]; prz[c] = pb[idx * 3 + 2];
        tx[c]  = tb[idx * 3 + 0]; ty[c]  = tb[idx * 3 + 1]; tz[c]  = tb[idx * 3 + 2];
        upc[c] = 0.f; Tv[c] = 0.f; vsave[c] = 0.f;
        rxc[c] = 0.f; ryc[c] = 0.f; rzc[c] = 0.f;
        colu[c] = (unsigned int)idx;
        freem[c] = ~0ull;
    }

    // ---- Phase 1a: column reduction. vv[c] = min_r d(r, col), colrow = argmin ----
    float colmin[4] = {BIGF, BIGF, BIGF, BIGF};
    int   colrow[4] = {0, 0, 0, 0};
#pragma unroll
    for (int rs = 0; rs < 4; ++rs) {
        for (int rl = 0; rl < 64; ++rl) {
            float bx = rlane(prx[rs], rl), by = rlane(pry[rs], rl), bz = rlane(prz[rs], rl);
            int r = rs * 64 + rl;
#pragma unroll
            for (int c = 0; c < 4; ++c) {
                float dx = bx - tx[c], dy = by - ty[c], dz = bz - tz[c];
                float d = rawsqrt(dx * dx + dy * dy + dz * dz);
                if (d < colmin[c]) { colmin[c] = d; colrow[c] = r; }
            }
        }
    }
#pragma unroll
    for (int c = 0; c < 4; ++c) vv[c] = colmin[c];

    // ---- Phase 1b: greedy claim — column (ascending) claims its argmin row if free ----
    unsigned long long frm[4];         // free-row masks (wave-uniform values)
    frm[0] = frm[1] = frm[2] = frm[3] = ~0ull;
#pragma unroll
    for (int cs = 0; cs < 4; ++cs) {
        for (int l = 0; l < 64; ++l) {
            int r = rlanei(colrow[cs], l);
            int rs = r >> 6, rl2 = r & 63;
            unsigned long long bit = 1ull << rl2;
            bool free_row = (SEL4(frm, rs) & bit) != 0ull;
            if (free_row) {
#pragma unroll
                for (int s = 0; s < 4; ++s)
                    if (s == rs) frm[s] &= ~bit;
                float bx, by, bz;
                switch (rs) {
                    case 0:  bx = rlane(prx[0], rl2); by = rlane(pry[0], rl2); bz = rlane(prz[0], rl2); break;
                    case 1:  bx = rlane(prx[1], rl2); by = rlane(pry[1], rl2); bz = rlane(prz[1], rl2); break;
                    case 2:  bx = rlane(prx[2], rl2); by = rlane(pry[2], rl2); bz = rlane(prz[2], rl2); break;
                    default: bx = rlane(prx[3], rl2); by = rlane(pry[3], rl2); bz = rlane(prz[3], rl2); break;
                }
                if (lane == l) {
                    pc[cs] = r; upc[cs] = 0.f;
                    rxc[cs] = bx; ryc[cs] = by; rzc[cs] = bz;
                }
#pragma unroll
                for (int s = 0; s < 4; ++s)
                    if (s == cs) freem[s] &= ~(1ull << l);   // column cs*64+l matched
            }
        }
    }

    // ---- Phase 2 (R15): multi-source successive-shortest-path searches ----
    while (frm[0] | frm[1] | frm[2] | frm[3]) {
        // Per-search init: fresh keys, way=-1 (parent = super-source), w = -v
        // (u=0 for all sources; keys are cumulative reduced distance).
#pragma unroll
        for (int c = 0; c < 4; ++c) {
            kMv[c]   = KBIG | colu[c];
            way[c]   = -1;
            srcrow[c] = -1;
            w[c]     = -vv[c];
        }

        // Multi-source seed sweep: every free row relaxes all 256 columns.
#pragma unroll
        for (int is = 0; is < 4; ++is) {
            unsigned long long m = frm[is];
            while (m) {
                const int il = (int)__builtin_ctzll(m);
                m &= (m - 1);
                const float sx = rlane(prx[is], il);
                const float sy = rlane(pry[is], il);
                const float sz = rlane(prz[is], il);
                const int r = is * 64 + il;
#pragma unroll
                for (int c = 0; c < 4; ++c) {
                    float dx = sx - tx[c], dy = sy - ty[c], dz = sz - tz[c];
                    float d = rawsqrt(dx * dx + dy * dy + dz * dz);
                    float cand = d + w[c];                       // d - v >= 0
                    unsigned int kc = (__float_as_uint(cand) & 0xFFFFFF00u) | colu[c];
                    if (kc < kMv[c]) { kMv[c] = kc; srcrow[c] = r; }
                }
            }
        }

        int usedm = 0;
        float bx, by, bz;
        int j0 = -1;
        int jfin = 0;
        float D = 0.f;

        while (true) {
            EXTRACT_ONCE
            RELAX_ONCE
            EXTRACT_ONCE
            RELAX_ONCE
        }

        // Commit duals for tree columns: net amount = D_final - D_at_use
#pragma unroll
        for (int c = 0; c < 4; ++c)
            if ((usedm >> c) & 1) {
                vv[c] = vsave[c] + Tv[c] - D;
                upc[c] += D - Tv[c];
            }

        // Newly matched column leaves the free set
        {
            const int wsl = jfin >> 6;
            const unsigned long long bit = 1ull << (jfin & 63);
#pragma unroll
            for (int s = 0; s < 4; ++s)
                if (s == wsl) freem[s] &= ~bit;
        }

        // Augment along alternating path (cold). way==-1 => edge came straight
        // from the seeding free row srcrow[jc]; that row gets u = D and leaves
        // the free-row set.
        int jc = jfin;
        while (true) {
            const int osl = jc >> 6, oln = jc & 63;
            int jw;
            switch (osl) {
                case 0:  jw = rlanei(way[0], oln); break;
                case 1:  jw = rlanei(way[1], oln); break;
                case 2:  jw = rlanei(way[2], oln); break;
                default: jw = rlanei(way[3], oln); break;
            }
            int np_; float nup, nrx, nry, nrz;
            if (jw < 0) {
                int sr;
                switch (osl) {
                    case 0:  sr = rlanei(srcrow[0], oln); break;
                    case 1:  sr = rlanei(srcrow[1], oln); break;
                    case 2:  sr = rlanei(srcrow[2], oln); break;
                    default: sr = rlanei(srcrow[3], oln); break;
                }
                const int ss = sr >> 6, sl = sr & 63;
                switch (ss) {
                    case 0:  nrx = rlane(prx[0], sl); nry = rlane(pry[0], sl); nrz = rlane(prz[0], sl); break;
                    case 1:  nrx = rlane(prx[1], sl); nry = rlane(pry[1], sl); nrz = rlane(prz[1], sl); break;
                    case 2:  nrx = rlane(prx[2], sl); nry = rlane(pry[2], sl); nrz = rlane(prz[2], sl); break;
                    default: nrx = rlane(prx[3], sl); nry = rlane(pry[3], sl); nrz = rlane(prz[3], sl); break;
                }
                np_ = sr; nup = D;
                const unsigned long long bit = 1ull << sl;
#pragma unroll
                for (int q = 0; q < 4; ++q)
                    if (q == ss) frm[q] &= ~bit;               // source row matched
            } else {
                const int wsl = jw >> 6, wln = jw & 63;
                switch (wsl) {
                    case 0:  np_ = rlanei(pc[0], wln); nup = rlane(upc[0], wln); nrx = rlane(rxc[0], wln); nry = rlane(ryc[0], wln); nrz = rlane(rzc[0], wln); break;
                    case 1:  np_ = rlanei(pc[1], wln); nup = rlane(upc[1], wln); nrx = rlane(rxc[1], wln); nry = rlane(ryc[1], wln); nrz = rlane(rzc[1], wln); break;
                    case 2:  np_ = rlanei(pc[2], wln); nup = rlane(upc[2], wln); nrx = rlane(rxc[2], wln); nry = rlane(ryc[2], wln); nrz = rlane(rzc[2], wln); break;
                    default: np_ = rlanei(pc[3], wln); nup = rlane(upc[3], wln); nrx = rlane(rxc[3], wln); nry = rlane(ryc[3], wln); nrz = rlane(rzc[3], wln); break;
                }
            }
#pragma unroll
            for (int c = 0; c < 4; ++c)
                if (c == osl && lane == oln) {
                    pc[c] = np_; upc[c] = nup;
                    rxc[c] = nrx; ryc[c] = nry; rzc[c] = nrz;
                }
            if (jw < 0) break;
            jc = jw;
        }
    }

    // ---- Matched cost (coords column-attached; IEEE sqrt for final accuracy) ----
    float s = 0.f;
#pragma unroll
    for (int c = 0; c < 4; ++c) {
        float dx = rxc[c] - tx[c], dy = ryc[c] - ty[c], dz = rzc[c] - tz[c];
        s += sqrtf(dx * dx + dy * dy + dz * dz);
    }
#pragma unroll
    for (int off = 1; off < 64; off <<= 1) s += __shfl_xor(s, off, 64);
    if (lane == 0) atomicAdd(out, s / (float)NBATCH);
}

extern "C" void kernel_launch(void* const* d_in, const int* in_sizes, int n_in,
                              void* d_out, int out_size, void* d_ws, size_t ws_size,
                              hipStream_t stream) {
    const float* pred   = (const float*)d_in[0];
    const float* target = (const float*)d_in[1];
    float* out = (float*)d_out;

    zero_out_kernel<<<1, 64, 0, stream>>>(out, out_size);
    hungarian_wave<<<NBATCH, 64, 0, stream>>>(pred, target, out);
}

// Round 3
// 1850.305 us; speedup vs baseline: 2.0729x; 2.0729x over previous
//
#include <hip/hip_runtime.h>

#define NPTS 256
#define NBATCH 64
#define BIGF 1e30f
#define KBIG 0x7149F200u   // __float_as_uint(1e30f) & 0xFFFFFF00

__device__ __forceinline__ float rlane(float v, int l) {
    return __uint_as_float((unsigned int)__builtin_amdgcn_readlane((int)__float_as_uint(v), l));
}
__device__ __forceinline__ int rlanei(int v, int l) {
    return __builtin_amdgcn_readlane(v, l);
}
__device__ __forceinline__ float rawsqrt(float x) {
    return __builtin_amdgcn_sqrtf(x);
}

// Uniform-slot select (slot wave-uniform); cold paths only.
#define SEL4(a, s) ((s) == 0 ? a[0] : (s) == 1 ? a[1] : (s) == 2 ? a[2] : a[3])

#define DPP_UMIN(v, ctrl) \
    (min)((v), (unsigned int)__builtin_amdgcn_update_dpp( \
        (int)(v), (int)(v), (ctrl), 0xf, 0xf, false))

// Full 64-lane packed-key min: 3 DPP row_shr (8-block minima at lanes 7,15,..,63)
// + 8 parallel readlanes + SALU min tree. Same shallow reduce as the hot loop.
#define REDUCE64(vrin, kkout)                                                     \
    {                                                                             \
        unsigned int _vr = (vrin);                                                \
        _vr = DPP_UMIN(_vr, 0x111);                                               \
        _vr = DPP_UMIN(_vr, 0x112);                                               \
        _vr = DPP_UMIN(_vr, 0x114);                                               \
        const unsigned int _q0 = (unsigned int)rlanei((int)_vr, 7);               \
        const unsigned int _q1 = (unsigned int)rlanei((int)_vr, 15);              \
        const unsigned int _q2 = (unsigned int)rlanei((int)_vr, 23);              \
        const unsigned int _q3 = (unsigned int)rlanei((int)_vr, 31);              \
        const unsigned int _q4 = (unsigned int)rlanei((int)_vr, 39);              \
        const unsigned int _q5 = (unsigned int)rlanei((int)_vr, 47);              \
        const unsigned int _q6 = (unsigned int)rlanei((int)_vr, 55);              \
        const unsigned int _q7 = (unsigned int)rlanei((int)_vr, 63);              \
        kkout = (min)((min)((min)(_q0, _q1), (min)(_q2, _q3)),                    \
                      (min)((min)(_q4, _q5), (min)(_q6, _q7)));                   \
    }

__global__ void zero_out_kernel(float* out, int n) {
    int i = blockIdx.x * blockDim.x + threadIdx.x;
    if (i < n) out[i] = 0.0f;
}

// One expansion step of the delta-accumulated Dijkstra (R10 dataflow).
// Reduce = 3 DPP row_shr (8-block minima in lanes 7,15,..,63) + 8 parallel
// readlanes + SALU min tree. `break` exits the enclosing while on augment.
#define EXPAND_ONCE                                                              \
    {                                                                            \
        _Pragma("unroll")                                                        \
        for (int c = 0; c < 4; ++c) {                                            \
            float dx = bx - tx[c], dy = by - ty[c], dz = bz - tz[c];             \
            float d = rawsqrt(dx * dx + dy * dy + dz * dz);                      \
            float cand = d + w[c];              /* == d - ukey - vv[c] */        \
            unsigned int kc = (__float_as_uint(cand) & 0xFFFFFF00u) | colu[c];   \
            if (kc < kMv[c]) { kMv[c] = kc; way[c] = j0; }                       \
        }                                                                        \
        unsigned int vr = (min)((min)(kMv[0], kMv[1]), (min)(kMv[2], kMv[3]));   \
        vr = DPP_UMIN(vr, 0x111);   /* row_shr:1 */                              \
        vr = DPP_UMIN(vr, 0x112);   /* row_shr:2 */                              \
        vr = DPP_UMIN(vr, 0x114);   /* row_shr:4 */                              \
        const unsigned int q0 = (unsigned int)rlanei((int)vr, 7);                \
        const unsigned int q1 = (unsigned int)rlanei((int)vr, 15);               \
        const unsigned int q2 = (unsigned int)rlanei((int)vr, 23);               \
        const unsigned int q3 = (unsigned int)rlanei((int)vr, 31);               \
        const unsigned int q4 = (unsigned int)rlanei((int)vr, 39);               \
        const unsigned int q5 = (unsigned int)rlanei((int)vr, 47);               \
        const unsigned int q6 = (unsigned int)rlanei((int)vr, 55);               \
        const unsigned int q7 = (unsigned int)rlanei((int)vr, 63);               \
        const unsigned int kk = (min)((min)((min)(q0, q1), (min)(q2, q3)),       \
                                      (min)((min)(q4, q5), (min)(q6, q7)));      \
        const int   j1   = (int)(kk & 0xFFu);                                    \
        const float gmin = __uint_as_float(kk & 0xFFFFFF00u);                    \
        const int osl = j1 >> 6, oln = j1 & 63;                                  \
        float uj, nbx, nby, nbz;                                                 \
        switch (osl) {                                                           \
            case 0:  uj = rlane(upc[0], oln); nbx = rlane(rxc[0], oln); nby = rlane(ryc[0], oln); nbz = rlane(rzc[0], oln); break; \
            case 1:  uj = rlane(upc[1], oln); nbx = rlane(rxc[1], oln); nby = rlane(ryc[1], oln); nbz = rlane(rzc[1], oln); break; \
            case 2:  uj = rlane(upc[2], oln); nbx = rlane(rxc[2], oln); nby = rlane(ryc[2], oln); nbz = rlane(rzc[2], oln); break; \
            default: uj = rlane(upc[3], oln); nbx = rlane(rxc[3], oln); nby = rlane(ryc[3], oln); nbz = rlane(rzc[3], oln); break; \
        }                                                                        \
        const unsigned long long fm =                                            \
            (osl == 0 ? freem[0] : osl == 1 ? freem[1] : osl == 2 ? freem[2] : freem[3]); \
        if ((fm >> oln) & 1ull) { jfin = j1; D = gmin; break; }                  \
        _Pragma("unroll")                                                        \
        for (int c = 0; c < 4; ++c)                                              \
            if (c == osl && lane == oln) {                                       \
                usedm |= (1 << c);                                               \
                Tv[c] = gmin;                                                    \
                vsave[c] = vv[c];                                                \
                vv[c] = -BIGF;                 /* -> w = +BIGF -> excluded */    \
                kMv[c] = KBIG | colu[c];       /* frozen */                      \
            }                                                                    \
        const float gu = gmin - uj;                                              \
        _Pragma("unroll")                                                        \
        for (int c = 0; c < 4; ++c) w[c] = gu - vv[c];                           \
        bx = nbx; by = nby; bz = nbz;                                            \
        j0 = j1;                                                                 \
    }

// One wave per batch; lane owns columns/rows {lane, 64+lane, 128+lane, 192+lane}.
// R16 = R13 base (R14 transfer/ARR falsified: +406us, chains budget-burn with
// ~no net matches; R15 multi-source falsified: +2000us, union-ball explores
// ~all columns per search) + Phase 1c: EXACT free-argmin claims.
// Structural fact (R13/14/15): every Dijkstra tree is near-complete (~256
// extractions), so Phase-2 time ~ F * 256 * chain. Only lever: reduce F.
// Phase 1c: for free row i, u_i = min_j (d - v_j) is feasible and tight at the
// argmin j*; if j* is FREE, matching (i,j*) preserves the JV invariant
// (feasible duals + tight matched edges) => exact, and eliminates one full
// search (~17us) per hit at ~150cy each.
__launch_bounds__(64, 1)
__global__ void hungarian_wave(const float* __restrict__ pred,
                               const float* __restrict__ target,
                               float* __restrict__ out) {
    const int b    = blockIdx.x;
    const int lane = threadIdx.x;

    const float* pb = pred   + (size_t)b * NPTS * 3;
    const float* tb = target + (size_t)b * NPTS * 3;

    float prx[4], pry[4], prz[4];      // pred (row) points, row = c*64+lane
    float tx[4], ty[4], tz[4];         // target (col) points, col = c*64+lane
    float vv[4], upc[4], Tv[4], w[4], vsave[4];
    float rxc[4], ryc[4], rzc[4];      // matched-row coords, column-attached
    unsigned int kMv[4];               // packed slack keys: (bits(M)&~0xFF)|col
    int   pc[4]  = {-1, -1, -1, -1};   // matched row per column (-1 = free)
    int   way[4];
    unsigned int colu[4];              // this lane's column ids
    unsigned long long freem[4];       // free-COLUMN masks (wave-uniform)

#pragma unroll
    for (int c = 0; c < 4; ++c) {
        int idx = c * 64 + lane;
        prx[c] = pb[idx * 3 + 0]; pry[c] = pb[idx * 3 + 1]; prz[c] = pb[idx * 3 + 2];
        tx[c]  = tb[idx * 3 + 0]; ty[c]  = tb[idx * 3 + 1]; tz[c]  = tb[idx * 3 + 2];
        upc[c] = 0.f; Tv[c] = 0.f; vsave[c] = 0.f;
        rxc[c] = 0.f; ryc[c] = 0.f; rzc[c] = 0.f;
        colu[c] = (unsigned int)idx;
        freem[c] = ~0ull;
    }

    // ---- Phase 1a: column reduction. vv[c] = min_r d(r, col), colrow = argmin ----
    float colmin[4] = {BIGF, BIGF, BIGF, BIGF};
    int   colrow[4] = {0, 0, 0, 0};
#pragma unroll
    for (int rs = 0; rs < 4; ++rs) {
        for (int rl = 0; rl < 64; ++rl) {
            float bx = rlane(prx[rs], rl), by = rlane(pry[rs], rl), bz = rlane(prz[rs], rl);
            int r = rs * 64 + rl;
#pragma unroll
            for (int c = 0; c < 4; ++c) {
                float dx = bx - tx[c], dy = by - ty[c], dz = bz - tz[c];
                float d = rawsqrt(dx * dx + dy * dy + dz * dz);
                if (d < colmin[c]) { colmin[c] = d; colrow[c] = r; }
            }
        }
    }
#pragma unroll
    for (int c = 0; c < 4; ++c) vv[c] = colmin[c];

    // ---- Phase 1b: greedy claim — column (ascending) claims its argmin row if free ----
    unsigned long long frm[4];         // free-row masks (wave-uniform values)
    frm[0] = frm[1] = frm[2] = frm[3] = ~0ull;
#pragma unroll
    for (int cs = 0; cs < 4; ++cs) {
        for (int l = 0; l < 64; ++l) {
            int r = rlanei(colrow[cs], l);
            int rs = r >> 6, rl2 = r & 63;
            unsigned long long bit = 1ull << rl2;
            bool free_row = (SEL4(frm, rs) & bit) != 0ull;
            if (free_row) {
#pragma unroll
                for (int s = 0; s < 4; ++s)
                    if (s == rs) frm[s] &= ~bit;
                float bx, by, bz;
                switch (rs) {
                    case 0:  bx = rlane(prx[0], rl2); by = rlane(pry[0], rl2); bz = rlane(prz[0], rl2); break;
                    case 1:  bx = rlane(prx[1], rl2); by = rlane(pry[1], rl2); bz = rlane(prz[1], rl2); break;
                    case 2:  bx = rlane(prx[2], rl2); by = rlane(pry[2], rl2); bz = rlane(prz[2], rl2); break;
                    default: bx = rlane(prx[3], rl2); by = rlane(pry[3], rl2); bz = rlane(prz[3], rl2); break;
                }
                if (lane == l) {
                    pc[cs] = r; upc[cs] = 0.f;
                    rxc[cs] = bx; ryc[cs] = by; rzc[cs] = bz;
                }
#pragma unroll
                for (int s = 0; s < 4; ++s)
                    if (s == cs) freem[s] &= ~(1ull << l);   // column cs*64+l matched
            }
        }
    }

    // ---- Phase 1c (R16): exact free-argmin claims ----
    // For each free row i: mu = min_j (d(i,j) - v_j). u_i = mu is feasible
    // (global row-min) and tight at argmin j*. If j* is free, match (i,j*):
    // invariant preserved, one full Dijkstra search eliminated.
#pragma unroll
    for (int is = 0; is < 4; ++is) {
        unsigned long long m = frm[is];
        while (m) {
            const int il = (int)__builtin_ctzll(m);
            m &= (m - 1);
            float cbx, cby, cbz;
            switch (is) {
                case 0:  cbx = rlane(prx[0], il); cby = rlane(pry[0], il); cbz = rlane(prz[0], il); break;
                case 1:  cbx = rlane(prx[1], il); cby = rlane(pry[1], il); cbz = rlane(prz[1], il); break;
                case 2:  cbx = rlane(prx[2], il); cby = rlane(pry[2], il); cbz = rlane(prz[2], il); break;
                default: cbx = rlane(prx[3], il); cby = rlane(pry[3], il); cbz = rlane(prz[3], il); break;
            }
            unsigned int ka[4];
#pragma unroll
            for (int c = 0; c < 4; ++c) {
                float dx = cbx - tx[c], dy = cby - ty[c], dz = cbz - tz[c];
                float r = rawsqrt(dx * dx + dy * dy + dz * dz) - vv[c];
                ka[c] = (__float_as_uint(r) & 0xFFFFFF00u) | colu[c];
            }
            unsigned int vra = (min)((min)(ka[0], ka[1]), (min)(ka[2], ka[3]));
            unsigned int kk;
            REDUCE64(vra, kk);
            const int jstar = (int)(kk & 0xFFu);
            const int osl = jstar >> 6, oln = jstar & 63;
            const unsigned long long fm = SEL4(freem, osl);
            if ((fm >> oln) & 1ull) {
                const float mu = __uint_as_float(kk & 0xFFFFFF00u);
                const int r = is * 64 + il;
#pragma unroll
                for (int c = 0; c < 4; ++c)
                    if (c == osl && lane == oln) {
                        pc[c] = r; upc[c] = mu;
                        rxc[c] = cbx; ryc[c] = cby; rzc[c] = cbz;
                    }
#pragma unroll
                for (int s = 0; s < 4; ++s)
                    if (s == osl) freem[s] &= ~(1ull << oln);
#pragma unroll
                for (int s = 0; s < 4; ++s)
                    if (s == is) frm[s] &= ~(1ull << il);
            }
        }
    }

    // ---- Phase 2: Dijkstra shortest-path for remaining free rows ----
#pragma unroll
    for (int is = 0; is < 4; ++is) {
        unsigned long long m = frm[is];
        while (m) {
            const int il = (int)__builtin_ctzll(m);
            m &= (m - 1);
            const int i = is * 64 + il;

            float rootx, rooty, rootz;
            switch (is) {
                case 0:  rootx = rlane(prx[0], il); rooty = rlane(pry[0], il); rootz = rlane(prz[0], il); break;
                case 1:  rootx = rlane(prx[1], il); rooty = rlane(pry[1], il); rootz = rlane(prz[1], il); break;
                case 2:  rootx = rlane(prx[2], il); rooty = rlane(pry[2], il); rootz = rlane(prz[2], il); break;
                default: rootx = rlane(prx[3], il); rooty = rlane(pry[3], il); rootz = rlane(prz[3], il); break;
            }

#pragma unroll
            for (int c = 0; c < 4; ++c) {
                kMv[c] = KBIG | colu[c];
                w[c]   = -vv[c];
            }
            int usedm = 0;

            float bx = rootx, by = rooty, bz = rootz;
            int j0 = -1;
            int jfin = 0;
            float D = 0.f;

            while (true) {
                EXPAND_ONCE
                EXPAND_ONCE
            }

            // Commit duals for tree columns: net amount = D_final - D_at_use
#pragma unroll
            for (int c = 0; c < 4; ++c)
                if ((usedm >> c) & 1) {
                    vv[c] = vsave[c] + Tv[c] - D;
                    upc[c] += D - Tv[c];
                }

            // Newly matched column leaves the free set
            {
                const int wsl = jfin >> 6;
                const unsigned long long bit = 1ull << (jfin & 63);
#pragma unroll
                for (int s = 0; s < 4; ++s)
                    if (s == wsl) freem[s] &= ~bit;
            }

            // Augment along alternating path (cold)
            int jc = jfin;
            while (true) {
                const int osl = jc >> 6, oln = jc & 63;
                int jw;
                switch (osl) {
                    case 0:  jw = rlanei(way[0], oln); break;
                    case 1:  jw = rlanei(way[1], oln); break;
                    case 2:  jw = rlanei(way[2], oln); break;
                    default: jw = rlanei(way[3], oln); break;
                }
                int np_; float nup, nrx, nry, nrz;
                if (jw < 0) {
                    np_ = i; nup = D; nrx = rootx; nry = rooty; nrz = rootz;
                } else {
                    const int wsl = jw >> 6, wln = jw & 63;
                    switch (wsl) {
                        case 0:  np_ = rlanei(pc[0], wln); nup = rlane(upc[0], wln); nrx = rlane(rxc[0], wln); nry = rlane(ryc[0], wln); nrz = rlane(rzc[0], wln); break;
                        case 1:  np_ = rlanei(pc[1], wln); nup = rlane(upc[1], wln); nrx = rlane(rxc[1], wln); nry = rlane(ryc[1], wln); nrz = rlane(rzc[1], wln); break;
                        case 2:  np_ = rlanei(pc[2], wln); nup = rlane(upc[2], wln); nrx = rlane(rxc[2], wln); nry = rlane(ryc[2], wln); nrz = rlane(rzc[2], wln); break;
                        default: np_ = rlanei(pc[3], wln); nup = rlane(upc[3], wln); nrx = rlane(rxc[3], wln); nry = rlane(ryc[3], wln); nrz = rlane(rzc[3], wln); break;
                    }
                }
#pragma unroll
                for (int c = 0; c < 4; ++c)
                    if (c == osl && lane == oln) {
                        pc[c] = np_; upc[c] = nup;
                        rxc[c] = nrx; ryc[c] = nry; rzc[c] = nrz;
                    }
                if (jw < 0) break;
                jc = jw;
            }
        }
    }

    // ---- Matched cost (coords column-attached; IEEE sqrt for final accuracy) ----
    float s = 0.f;
#pragma unroll
    for (int c = 0; c < 4; ++c) {
        float dx = rxc[c] - tx[c], dy = ryc[c] - ty[c], dz = rzc[c] - tz[c];
        s += sqrtf(dx * dx + dy * dy + dz * dz);
    }
#pragma unroll
    for (int off = 1; off < 64; off <<= 1) s += __shfl_xor(s, off, 64);
    if (lane == 0) atomicAdd(out, s / (float)NBATCH);
}

extern "C" void kernel_launch(void* const* d_in, const int* in_sizes, int n_in,
                              void* d_out, int out_size, void* d_ws, size_t ws_size,
                              hipStream_t stream) {
    const float* pred   = (const float*)d_in[0];
    const float* target = (const float*)d_in[1];
    float* out = (float*)d_out;

    zero_out_kernel<<<1, 64, 0, stream>>>(out, out_size);
    hungarian_wave<<<NBATCH, 64, 0, stream>>>(pred, target, out);
}